// Round 1
// baseline (353.001 us; speedup 1.0000x reference)
//
#include <hip/hip_runtime.h>

// Self-attention, B=4 S=2048 D=1024 H=16 Hd=64, fp32 in/out, bf16 MFMA inside.
// Pipeline: cvt(fp32->bf16) -> GEMM QKV (fused, Q*0.125) -> flash attn -> GEMM out+bias.

typedef unsigned short u16;
typedef float f32x4 __attribute__((ext_vector_type(4)));
typedef short s16x8 __attribute__((ext_vector_type(8)));

#define DEVI __device__ __forceinline__

DEVI u16 f32_bf16(float f) {
  unsigned u = __float_as_uint(f);
  return (u16)((u + 0x7FFFu + ((u >> 16) & 1u)) >> 16);
}

DEVI void gload_lds16(const void* g, void* l) {
  // 16B per lane, LDS dest = wave-uniform base + lane*16
  __builtin_amdgcn_global_load_lds((const __attribute__((address_space(1))) void*)g,
                                   (__attribute__((address_space(3))) void*)l, 16, 0, 0);
}

// ---------------- fp32 -> bf16 conversion ----------------
__global__ void cvt_kernel(const float* __restrict__ in, u16* __restrict__ out, int n4) {
  int i = blockIdx.x * 256 + threadIdx.x;
  if (i >= n4) return;
  float4 v = ((const float4*)in)[i];
  ushort4 o;
  o.x = f32_bf16(v.x); o.y = f32_bf16(v.y);
  o.z = f32_bf16(v.z); o.w = f32_bf16(v.w);
  ((ushort4*)out)[i] = o;
}

// ---------------- B^T GEMM: C[M,N] = A[M,K] * B[N,K]^T ----------------
// 128x128 tile, BK=32, 256 threads (4 waves, 2x2 of 64x64), 16x16x32 bf16 MFMA.
// MODE 0: bf16 out, cols<1024 scaled by 0.125 (Q scale). MODE 1: fp32 out + bias.
template <int MODE>
__global__ __launch_bounds__(256, 2) void gemm_bt(
    const u16* __restrict__ A, const u16* __restrict__ B, void* __restrict__ Cout,
    const float* __restrict__ bias, int M, int N, int K) {
  __shared__ u16 As[128 * 32];
  __shared__ u16 Bs[128 * 32];
  const int tid = threadIdx.x;
  const int lane = tid & 63;
  const int w = tid >> 6;
  const int wr = w >> 1, wc = w & 1;
  const int l15 = lane & 15, l4 = lane >> 4;
  const int m0 = blockIdx.y * 128, n0 = blockIdx.x * 128;

  f32x4 acc[4][4] = {};

  for (int k0 = 0; k0 < K; k0 += 32) {
    __syncthreads();  // previous compute done before LDS overwrite
#pragma unroll
    for (int i = 0; i < 2; ++i) {
      int cb = i * 256 + w * 64;  // wave-uniform chunk base
      int c = cb + lane;          // chunk: row=c>>2, k-offset=(c&3)*8
      gload_lds16(A + (m0 + (c >> 2)) * K + k0 + (c & 3) * 8, &As[cb * 8]);
      gload_lds16(B + (n0 + (c >> 2)) * K + k0 + (c & 3) * 8, &Bs[cb * 8]);
    }
    __syncthreads();  // drains vmcnt(0) incl. global_load_lds

    s16x8 af[4], bf[4];
#pragma unroll
    for (int m = 0; m < 4; ++m)
      af[m] = *(const s16x8*)&As[(wr * 64 + m * 16 + l15) * 32 + l4 * 8];
#pragma unroll
    for (int n = 0; n < 4; ++n)
      bf[n] = *(const s16x8*)&Bs[(wc * 64 + n * 16 + l15) * 32 + l4 * 8];
#pragma unroll
    for (int m = 0; m < 4; ++m)
#pragma unroll
      for (int n = 0; n < 4; ++n)
        acc[m][n] = __builtin_amdgcn_mfma_f32_16x16x32_bf16(af[m], bf[n], acc[m][n], 0, 0, 0);
  }

  // epilogue: C/D layout col=lane&15, row=(lane>>4)*4+reg
#pragma unroll
  for (int m = 0; m < 4; ++m) {
    int row = m0 + wr * 64 + m * 16 + l4 * 4;
#pragma unroll
    for (int n = 0; n < 4; ++n) {
      int col = n0 + wc * 64 + n * 16 + l15;
      if (MODE == 0) {
        u16* C = (u16*)Cout;
        float scale = (col < 1024) ? 0.125f : 1.0f;
#pragma unroll
        for (int j = 0; j < 4; ++j)
          C[(row + j) * N + col] = f32_bf16(acc[m][n][j] * scale);
      } else {
        float* C = (float*)Cout;
        float bb = bias[col];
#pragma unroll
        for (int j = 0; j < 4; ++j)
          C[(row + j) * N + col] = acc[m][n][j] + bb;
      }
    }
  }
}

// ---------------- flash attention ----------------
// QKV: [8192, 3072] bf16 rows = [Q(1024, pre-scaled 1/8) | K(1024) | V(1024)].
// Block: (qt,h,b), 256 thr = 4 waves; wave w owns q-rows q0+w*16..+15, full Hd=64.
// K-tile = 64 keys. LDS rows padded to 72 elems (144B) -> conflict-free-ish ds_read_b128.
__global__ __launch_bounds__(256, 2) void attn_kernel(const u16* __restrict__ QKV,
                                                      u16* __restrict__ AO) {
  __shared__ u16 Ks[64 * 72];      // K rows   [kk][d]
  __shared__ u16 Vt[64 * 72];      // V transposed [d][kk]
  __shared__ u16 Ps[4][16 * 72];   // per-wave P tile [q][k]
  const int tid = threadIdx.x;
  const int lane = tid & 63, w = tid >> 6;
  const int l15 = lane & 15, l4 = lane >> 4;
  const int q0 = blockIdx.x * 64, h = blockIdx.y, b = blockIdx.z;
  const int rowbase = b * 2048;
  const float L2E = 1.44269504f;

  // hoist Q fragments (A-frag: row=lane&15, k=(lane>>4)*8, two k-steps of 32)
  s16x8 qa[2];
  {
    const u16* qp = QKV + (rowbase + q0 + w * 16 + l15) * 3072 + h * 64 + l4 * 8;
    qa[0] = *(const s16x8*)qp;
    qa[1] = *(const s16x8*)(qp + 32);
  }

  f32x4 o[4] = {};
  float mrow[4], lrow[4];
#pragma unroll
  for (int j = 0; j < 4; ++j) { mrow[j] = -1e30f; lrow[j] = 0.f; }

  const int kkK = tid >> 2, d0K = (tid & 3) * 16;        // K staging: row kkK, 16 cols
  const int kkV = (tid & 31) * 2, d0V = (tid >> 5) * 8;  // V staging: 2 rows, 8 cols

  for (int kt = 0; kt < 32; ++kt) {
    const int k0 = kt * 64;
    __syncthreads();  // prior tile reads done
    {  // stage K rows (row-major, padded)
      const u16* kp = QKV + (rowbase + k0 + kkK) * 3072 + 1024 + h * 64 + d0K;
      s16x8 r0 = *(const s16x8*)kp;
      s16x8 r1 = *(const s16x8*)(kp + 8);
      *(s16x8*)&Ks[kkK * 72 + d0K] = r0;
      *(s16x8*)&Ks[kkK * 72 + d0K + 8] = r1;
    }
    {  // stage V transposed: Vt[d][kk]
      const u16* vp = QKV + (rowbase + k0 + kkV) * 3072 + 2048 + h * 64 + d0V;
      s16x8 r0 = *(const s16x8*)vp;
      s16x8 r1 = *(const s16x8*)(vp + 3072);
#pragma unroll
      for (int i = 0; i < 8; ++i) {
        unsigned v0 = (u16)r0[i], v1 = (u16)r1[i];
        *(unsigned*)&Vt[(d0V + i) * 72 + kkV] = v0 | (v1 << 16);
      }
    }
    __syncthreads();

    // S = Q*K^T (pre-scaled): B-frag lane: K[k0 + n*16 + (l&15)][(l>>4)*8 + 32*ks]
    f32x4 sc[4] = {};
#pragma unroll
    for (int ks = 0; ks < 2; ++ks)
#pragma unroll
      for (int n = 0; n < 4; ++n) {
        s16x8 kb = *(const s16x8*)&Ks[(n * 16 + l15) * 72 + ks * 32 + l4 * 8];
        sc[n] = __builtin_amdgcn_mfma_f32_16x16x32_bf16(qa[ks], kb, sc[n], 0, 0, 0);
      }

    // online softmax; D-layout: row=(l>>4)*4+j, col=n*16+(l&15)
    float p[4][4];
#pragma unroll
    for (int j = 0; j < 4; ++j) {
      float m4 = fmaxf(fmaxf(sc[0][j], sc[1][j]), fmaxf(sc[2][j], sc[3][j]));
#pragma unroll
      for (int mask = 1; mask <= 8; mask <<= 1) m4 = fmaxf(m4, __shfl_xor(m4, mask));
      float mnew = fmaxf(mrow[j], m4);
      float corr = exp2f((mrow[j] - mnew) * L2E);
      float rs = 0.f;
#pragma unroll
      for (int n = 0; n < 4; ++n) {
        float pv = exp2f((sc[n][j] - mnew) * L2E);
        p[n][j] = pv; rs += pv;
      }
#pragma unroll
      for (int mask = 1; mask <= 8; mask <<= 1) rs += __shfl_xor(rs, mask);
      lrow[j] = lrow[j] * corr + rs;
      mrow[j] = mnew;
#pragma unroll
      for (int nd = 0; nd < 4; ++nd) o[nd][j] *= corr;
    }

    // P (D-layout) -> per-wave LDS -> reload as A-frag layout
    u16* psw = &Ps[w][0];
#pragma unroll
    for (int n = 0; n < 4; ++n)
#pragma unroll
      for (int j = 0; j < 4; ++j)
        psw[(l4 * 4 + j) * 72 + n * 16 + l15] = f32_bf16(p[n][j]);
    s16x8 pa0 = *(const s16x8*)&psw[l15 * 72 + l4 * 8];
    s16x8 pa1 = *(const s16x8*)&psw[l15 * 72 + 32 + l4 * 8];

    // O += P*V: B-frag lane: V[k0 + 32*ks + (l>>4)*8 + j][nd*16 + (l&15)] = Vt[col][k]
#pragma unroll
    for (int nd = 0; nd < 4; ++nd) {
      s16x8 vb0 = *(const s16x8*)&Vt[(nd * 16 + l15) * 72 + l4 * 8];
      o[nd] = __builtin_amdgcn_mfma_f32_16x16x32_bf16(pa0, vb0, o[nd], 0, 0, 0);
      s16x8 vb1 = *(const s16x8*)&Vt[(nd * 16 + l15) * 72 + 32 + l4 * 8];
      o[nd] = __builtin_amdgcn_mfma_f32_16x16x32_bf16(pa1, vb1, o[nd], 0, 0, 0);
    }
  }

  // finalize: divide by row sum, store bf16
#pragma unroll
  for (int nd = 0; nd < 4; ++nd)
#pragma unroll
    for (int j = 0; j < 4; ++j) {
      int row = rowbase + q0 + w * 16 + l4 * 4 + j;
      AO[row * 1024 + h * 64 + nd * 16 + l15] = f32_bf16(o[nd][j] / lrow[j]);
    }
}

// ---------------- launch ----------------
extern "C" void kernel_launch(void* const* d_in, const int* in_sizes, int n_in,
                              void* d_out, int out_size, void* d_ws, size_t ws_size,
                              hipStream_t stream) {
  const float* x = (const float*)d_in[0];
  const float* Wq = (const float*)d_in[1];
  const float* Wk = (const float*)d_in[2];
  const float* Wv = (const float*)d_in[3];
  const float* Wo = (const float*)d_in[4];
  const float* bo = (const float*)d_in[5];
  float* out = (float*)d_out;

  char* ws = (char*)d_ws;
  u16* x_bf = (u16*)ws;                                   // 8192*1024*2   = 16.8 MB
  u16* Wcat = (u16*)(ws + 16777216);                      // 3072*1024*2  =  6.3 MB
  u16* Wo_bf = (u16*)(ws + 16777216 + 6291456);           // 1024*1024*2  =  2.1 MB
  u16* QKV = (u16*)(ws + 16777216 + 6291456 + 2097152);   // 8192*3072*2  = 50.3 MB
  u16* AO = (u16*)(ws + 16777216 + 6291456 + 2097152 + 50331648);  // 16.8 MB

  cvt_kernel<<<8192, 256, 0, stream>>>(x, x_bf, 8192 * 1024 / 4);
  cvt_kernel<<<1024, 256, 0, stream>>>(Wq, Wcat, 1024 * 1024 / 4);
  cvt_kernel<<<1024, 256, 0, stream>>>(Wk, Wcat + 1024 * 1024, 1024 * 1024 / 4);
  cvt_kernel<<<1024, 256, 0, stream>>>(Wv, Wcat + 2 * 1024 * 1024, 1024 * 1024 / 4);
  cvt_kernel<<<1024, 256, 0, stream>>>(Wo, Wo_bf, 1024 * 1024 / 4);

  // QKV = x_bf @ Wcat^T  [8192, 3072] (Q cols scaled by 1/8)
  gemm_bt<0><<<dim3(24, 64), 256, 0, stream>>>(x_bf, Wcat, QKV, nullptr, 8192, 3072, 1024);
  // flash attention -> AO [8192, 1024] bf16
  attn_kernel<<<dim3(32, 16, 4), 256, 0, stream>>>(QKV, AO);
  // out = AO @ Wo^T + bo  [8192, 1024] fp32
  gemm_bt<1><<<dim3(8, 64), 256, 0, stream>>>(AO, Wo_bf, out, bo, 8192, 1024, 1024);
}

// Round 2
// 257.415 us; speedup vs baseline: 1.3713x; 1.3713x over previous
//
#include <hip/hip_runtime.h>

// Self-attention, B=4 S=2048 D=1024 H=16 Hd=64, fp32 in/out, bf16 MFMA inside.
// Pipeline: cvt(fp32->bf16) -> GEMM QKV (fused, Q*0.125*log2e) -> flash attn (swapped
// QK^T, lane-local softmax, log2 domain, defer-max, async staging) -> GEMM out+bias.

typedef unsigned short u16;
typedef float f32x4 __attribute__((ext_vector_type(4)));
typedef short s16x8 __attribute__((ext_vector_type(8)));

#define DEVI __device__ __forceinline__

DEVI u16 f32_bf16(float f) {
  unsigned u = __float_as_uint(f);
  return (u16)((u + 0x7FFFu + ((u >> 16) & 1u)) >> 16);
}

DEVI unsigned pack_bf16(float a, float b) {
  return (unsigned)f32_bf16(a) | ((unsigned)f32_bf16(b) << 16);
}

DEVI void gload_lds16(const void* g, void* l) {
  __builtin_amdgcn_global_load_lds((const __attribute__((address_space(1))) void*)g,
                                   (__attribute__((address_space(3))) void*)l, 16, 0, 0);
}

// ---------------- fp32 -> bf16 conversion ----------------
__global__ void cvt_kernel(const float* __restrict__ in, u16* __restrict__ out, int n4) {
  int i = blockIdx.x * 256 + threadIdx.x;
  if (i >= n4) return;
  float4 v = ((const float4*)in)[i];
  ushort4 o;
  o.x = f32_bf16(v.x); o.y = f32_bf16(v.y);
  o.z = f32_bf16(v.z); o.w = f32_bf16(v.w);
  ((ushort4*)out)[i] = o;
}

// ---------------- B^T GEMM: C[M,N] = A[M,K] * B[N,K]^T ----------------
// 128x128 tile, BK=32, 256 threads (4 waves, 2x2 of 64x64), 16x16x32 bf16 MFMA.
// MODE 0: bf16 out, cols<1024 scaled by 0.125*log2(e) (Q scale, log2 domain).
// MODE 1: fp32 out + bias.
template <int MODE>
__global__ __launch_bounds__(256, 2) void gemm_bt(
    const u16* __restrict__ A, const u16* __restrict__ B, void* __restrict__ Cout,
    const float* __restrict__ bias, int M, int N, int K) {
  __shared__ u16 As[128 * 32];
  __shared__ u16 Bs[128 * 32];
  const int tid = threadIdx.x;
  const int lane = tid & 63;
  const int w = tid >> 6;
  const int wr = w >> 1, wc = w & 1;
  const int l15 = lane & 15, l4 = lane >> 4;
  const int m0 = blockIdx.y * 128, n0 = blockIdx.x * 128;

  f32x4 acc[4][4] = {};

  for (int k0 = 0; k0 < K; k0 += 32) {
    __syncthreads();
#pragma unroll
    for (int i = 0; i < 2; ++i) {
      int cb = i * 256 + w * 64;
      int c = cb + lane;
      gload_lds16(A + (m0 + (c >> 2)) * K + k0 + (c & 3) * 8, &As[cb * 8]);
      gload_lds16(B + (n0 + (c >> 2)) * K + k0 + (c & 3) * 8, &Bs[cb * 8]);
    }
    __syncthreads();

    s16x8 af[4], bf[4];
#pragma unroll
    for (int m = 0; m < 4; ++m)
      af[m] = *(const s16x8*)&As[(wr * 64 + m * 16 + l15) * 32 + l4 * 8];
#pragma unroll
    for (int n = 0; n < 4; ++n)
      bf[n] = *(const s16x8*)&Bs[(wc * 64 + n * 16 + l15) * 32 + l4 * 8];
#pragma unroll
    for (int m = 0; m < 4; ++m)
#pragma unroll
      for (int n = 0; n < 4; ++n)
        acc[m][n] = __builtin_amdgcn_mfma_f32_16x16x32_bf16(af[m], bf[n], acc[m][n], 0, 0, 0);
  }

#pragma unroll
  for (int m = 0; m < 4; ++m) {
    int row = m0 + wr * 64 + m * 16 + l4 * 4;
#pragma unroll
    for (int n = 0; n < 4; ++n) {
      int col = n0 + wc * 64 + n * 16 + l15;
      if (MODE == 0) {
        u16* C = (u16*)Cout;
        float scale = (col < 1024) ? 0.18033688f : 1.0f;  // 0.125 * log2(e)
#pragma unroll
        for (int j = 0; j < 4; ++j)
          C[(row + j) * N + col] = f32_bf16(acc[m][n][j] * scale);
      } else {
        float* C = (float*)Cout;
        float bb = bias[col];
#pragma unroll
        for (int j = 0; j < 4; ++j)
          C[(row + j) * N + col] = acc[m][n][j] + bb;
      }
    }
  }
}

// ---------------- flash attention (swapped QK^T) ----------------
// QKV: [8192, 3072] bf16 = [Q*0.125*log2e | K | V]. Block (qt,h,b): 4 waves,
// wave w owns q-rows q0+w*16..+15. Per 64-key tile:
//   S^T = mfma(A=K, B=Q^T)  -> lane holds 16 scores, all for q = lane&15
//   softmax lane-local (log2 domain), 2 shuffles per reduce
//   P -> per-wave LDS row-major [q][k] (packed u32 writes), b128 B-frag reads
//   O^T += mfma(A=V^T(from Vt staging), B=P^T)
__global__ __launch_bounds__(256, 2) void attn_kernel(const u16* __restrict__ QKV,
                                                      u16* __restrict__ AO) {
  __shared__ u16 Ks[64 * 72];     // K rows [kk][d]
  __shared__ u16 Vt[64 * 72];     // V transposed [d][kk]
  __shared__ u16 Ps[4][16 * 72];  // per-wave P [q][k]
  const int tid = threadIdx.x;
  const int lane = tid & 63, w = tid >> 6;
  const int l15 = lane & 15, l4 = lane >> 4;
  const int q0 = blockIdx.x * 64, h = blockIdx.y, b = blockIdx.z;
  const int rowbase = b * 2048;

  // Q B-frag hoist: lane holds Q[q0+w*16+l15][l4*8 .. +7] (two 32-k slices)
  s16x8 qa[2];
  {
    const u16* qp = QKV + (rowbase + q0 + w * 16 + l15) * 3072 + h * 64 + l4 * 8;
    qa[0] = *(const s16x8*)qp;
    qa[1] = *(const s16x8*)(qp + 32);
  }

  f32x4 o[4] = {};
  float mrow = -1e30f, lrow = 0.f;

  const int kkK = tid >> 2, d0K = (tid & 3) * 16;
  const int kkV = (tid & 31) * 2, d0V = (tid >> 5) * 8;
  const u16* kbase = QKV + rowbase * 3072 + 1024 + h * 64;
  const u16* vbase = QKV + rowbase * 3072 + 2048 + h * 64;

  // prefetch tile 0 into registers
  s16x8 kc0, kc1, vc0, vc1;
  {
    const u16* kp = kbase + kkK * 3072 + d0K;
    kc0 = *(const s16x8*)kp;
    kc1 = *(const s16x8*)(kp + 8);
    const u16* vp = vbase + kkV * 3072 + d0V;
    vc0 = *(const s16x8*)vp;
    vc1 = *(const s16x8*)(vp + 3072);
  }

  for (int kt = 0; kt < 32; ++kt) {
    __syncthreads();  // all waves done reading prev tile's Ks/Vt
    // ---- write LDS from current regs ----
    *(s16x8*)&Ks[kkK * 72 + d0K] = kc0;
    *(s16x8*)&Ks[kkK * 72 + d0K + 8] = kc1;
#pragma unroll
    for (int i = 0; i < 8; ++i) {
      unsigned v0 = (u16)vc0[i], v1 = (u16)vc1[i];
      *(unsigned*)&Vt[(d0V + i) * 72 + kkV] = v0 | (v1 << 16);
    }
    // ---- issue next-tile global loads (latency hides under compute) ----
    if (kt < 31) {
      const u16* kp = kbase + ((kt + 1) * 64 + kkK) * 3072 + d0K;
      kc0 = *(const s16x8*)kp;
      kc1 = *(const s16x8*)(kp + 8);
      const u16* vp = vbase + ((kt + 1) * 64 + kkV) * 3072 + d0V;
      vc0 = *(const s16x8*)vp;
      vc1 = *(const s16x8*)(vp + 3072);
    }
    __syncthreads();

    // ---- S^T = K * Q^T : sc[m][j] = S[q=l15][key = m*16 + l4*4 + j] ----
    f32x4 sc[4] = {};
#pragma unroll
    for (int ks = 0; ks < 2; ++ks)
#pragma unroll
      for (int m = 0; m < 4; ++m) {
        s16x8 kb = *(const s16x8*)&Ks[(m * 16 + l15) * 72 + ks * 32 + l4 * 8];
        sc[m] = __builtin_amdgcn_mfma_f32_16x16x32_bf16(kb, qa[ks], sc[m], 0, 0, 0);
      }

    // ---- lane-local online softmax (log2 domain) ----
    float m4 = sc[0][0];
#pragma unroll
    for (int m = 0; m < 4; ++m)
#pragma unroll
      for (int j = 0; j < 4; ++j) m4 = fmaxf(m4, sc[m][j]);
    m4 = fmaxf(m4, __shfl_xor(m4, 16));
    m4 = fmaxf(m4, __shfl_xor(m4, 32));
    if (!__all(m4 <= mrow + 8.f)) {  // defer-max: skip rescale when growth small
      float mnew = fmaxf(mrow, m4);
      float corr = __builtin_amdgcn_exp2f(mrow - mnew);
      lrow *= corr;
#pragma unroll
      for (int nd = 0; nd < 4; ++nd)
#pragma unroll
        for (int j = 0; j < 4; ++j) o[nd][j] *= corr;
      mrow = mnew;
    }
    float p[4][4];
    float rs = 0.f;
#pragma unroll
    for (int m = 0; m < 4; ++m)
#pragma unroll
      for (int j = 0; j < 4; ++j) {
        float pv = __builtin_amdgcn_exp2f(sc[m][j] - mrow);
        p[m][j] = pv;
        rs += pv;
      }
    rs += __shfl_xor(rs, 16);
    rs += __shfl_xor(rs, 32);
    lrow += rs;

    // ---- P -> per-wave LDS [q][k], packed u32 writes ----
    u16* psw = &Ps[w][0];
#pragma unroll
    for (int m = 0; m < 4; ++m) {
      *(unsigned*)&psw[l15 * 72 + m * 16 + l4 * 4] = pack_bf16(p[m][0], p[m][1]);
      *(unsigned*)&psw[l15 * 72 + m * 16 + l4 * 4 + 2] = pack_bf16(p[m][2], p[m][3]);
    }
    s16x8 pb0 = *(const s16x8*)&psw[l15 * 72 + l4 * 8];
    s16x8 pb1 = *(const s16x8*)&psw[l15 * 72 + 32 + l4 * 8];

    // ---- O^T += V^T * P^T ----
#pragma unroll
    for (int nd = 0; nd < 4; ++nd) {
      s16x8 vb0 = *(const s16x8*)&Vt[(nd * 16 + l15) * 72 + l4 * 8];
      o[nd] = __builtin_amdgcn_mfma_f32_16x16x32_bf16(vb0, pb0, o[nd], 0, 0, 0);
      s16x8 vb1 = *(const s16x8*)&Vt[(nd * 16 + l15) * 72 + 32 + l4 * 8];
      o[nd] = __builtin_amdgcn_mfma_f32_16x16x32_bf16(vb1, pb1, o[nd], 0, 0, 0);
    }
  }

  // ---- finalize: O[q][d] = O^T/lrow, lane has q=l15, d=nd*16+l4*4+j ----
  float inv = __builtin_amdgcn_rcpf(lrow);
  const int orow = rowbase + q0 + w * 16 + l15;
#pragma unroll
  for (int nd = 0; nd < 4; ++nd) {
    ushort4 s;
    s.x = f32_bf16(o[nd][0] * inv);
    s.y = f32_bf16(o[nd][1] * inv);
    s.z = f32_bf16(o[nd][2] * inv);
    s.w = f32_bf16(o[nd][3] * inv);
    *(ushort4*)&AO[orow * 1024 + h * 64 + nd * 16 + l4 * 4] = s;
  }
}

// ---------------- launch ----------------
extern "C" void kernel_launch(void* const* d_in, const int* in_sizes, int n_in,
                              void* d_out, int out_size, void* d_ws, size_t ws_size,
                              hipStream_t stream) {
  const float* x = (const float*)d_in[0];
  const float* Wq = (const float*)d_in[1];
  const float* Wk = (const float*)d_in[2];
  const float* Wv = (const float*)d_in[3];
  const float* Wo = (const float*)d_in[4];
  const float* bo = (const float*)d_in[5];
  float* out = (float*)d_out;

  char* ws = (char*)d_ws;
  u16* x_bf = (u16*)ws;                                   // 16.8 MB
  u16* Wcat = (u16*)(ws + 16777216);                      //  6.3 MB
  u16* Wo_bf = (u16*)(ws + 16777216 + 6291456);           //  2.1 MB
  u16* QKV = (u16*)(ws + 16777216 + 6291456 + 2097152);   // 50.3 MB
  u16* AO = (u16*)(ws + 16777216 + 6291456 + 2097152 + 50331648);  // 16.8 MB

  cvt_kernel<<<8192, 256, 0, stream>>>(x, x_bf, 8192 * 1024 / 4);
  cvt_kernel<<<1024, 256, 0, stream>>>(Wq, Wcat, 1024 * 1024 / 4);
  cvt_kernel<<<1024, 256, 0, stream>>>(Wk, Wcat + 1024 * 1024, 1024 * 1024 / 4);
  cvt_kernel<<<1024, 256, 0, stream>>>(Wv, Wcat + 2 * 1024 * 1024, 1024 * 1024 / 4);
  cvt_kernel<<<1024, 256, 0, stream>>>(Wo, Wo_bf, 1024 * 1024 / 4);

  gemm_bt<0><<<dim3(24, 64), 256, 0, stream>>>(x_bf, Wcat, QKV, nullptr, 8192, 3072, 1024);
  attn_kernel<<<dim3(32, 16, 4), 256, 0, stream>>>(QKV, AO);
  gemm_bt<1><<<dim3(8, 64), 256, 0, stream>>>(AO, Wo_bf, out, bo, 8192, 1024, 1024);
}